// Round 4
// baseline (354.206 us; speedup 1.0000x reference)
//
#include <hip/hip_runtime.h>

typedef unsigned short u16;
typedef __attribute__((ext_vector_type(8))) short short8;
typedef __attribute__((ext_vector_type(4))) float float4v;

#define BTH (512*256*128)   // elements per output tensor
#define MASKV (-30000.0f)

__device__ __forceinline__ u16 f2bf(float f){
    union{float f; unsigned i;} v; v.f = f;
    unsigned x = v.i;
    unsigned r = (x + 0x7FFFu + ((x >> 16) & 1u)) >> 16;  // RNE
    return (u16)r;
}

// ---------------- Kernel 0: f32 weights -> bf16 WT[3][128 n][128 k]; fold C^-0.5 into Wq.
__global__ void wt_kernel(const float* __restrict__ Wq, const float* __restrict__ Wk,
                          const float* __restrict__ Wv, u16* __restrict__ WT){
    int idx = blockIdx.x * 256 + threadIdx.x;   // 0..49151
    int w   = idx >> 14;
    int rem = idx & 16383;
    int n = rem >> 7;
    int k = rem & 127;
    const float* src = (w == 0) ? Wq : (w == 1) ? Wk : Wv;
    float val = src[k * 128 + n];
    if (w == 0) val *= 0.08838834764831845f;    // 128^-0.5
    WT[idx] = f2bf(val);
}

// ============================================================================
// fused_kernel: one block = one batch (512 blocks x 512 threads = 8 waves).
// Projection (q,k,v = x@W), K and V^T images kept entirely in LDS, then
// causal attention with single-pass softmax (full 256-key S row in registers).
//
// LDS (128 KiB):
//   Kbuf  [4 ks][256 key][32]  bf16 (64 KB)  K permuted: Kbuf[h>>5][key][h&31]
//         -- also serves as per-wave 8 KB scratch for Q-transpose (before K
//            is written) and P-transpose (after QK^T, K dead).
//   VTbuf [8 ck][128 h][32]    bf16 (64 KB)  V^T permuted: VTbuf[t>>5][h][t&31]
// Both layouts give minimum-aliasing ds_read_b128 fragment reads (verified
// pattern from round-3 attn4).
//
// Wave w owns row-tiles rt_g = {w, w+8} (interleaved -> causal load balance).
// Work split is wave-uniform everywhere; 3 __syncthreads() total.
// ============================================================================
__global__ __launch_bounds__(512, 2) void fused_kernel(const float* __restrict__ x,
                                                       const u16* __restrict__ WT,
                                                       float* __restrict__ dout){
    __shared__ u16 Kbuf [4 * 256 * 32];   // 64 KB
    __shared__ u16 VTbuf[8 * 128 * 32];   // 64 KB

    int b = blockIdx.x;
    int tid = threadIdx.x;
    int w = tid >> 6, lane = tid & 63, lq = lane & 15, quad = lane >> 4;

    const float* xb   = x    + (size_t)b * 256 * 128;
    float*       oout = dout + (size_t)b * 256 * 128;
    float*       kout = dout + (size_t)BTH     + (size_t)b * 256 * 128;
    float*       vout = dout + (size_t)2 * BTH + (size_t)b * 256 * 128;

    const int rtg[2] = { w, w + 8 };      // this wave's global row-tile indices

    // ---- x fragments for own 32 rows (f32 -> bf16), registers only
    short8 ax[2][4];
    #pragma unroll
    for (int rt = 0; rt < 2; rt++){
        #pragma unroll
        for (int ks = 0; ks < 4; ks++){
            const float* px = xb + (size_t)(rtg[rt]*16 + lq)*128 + ks*32 + quad*8;
            float4v lo = *(const float4v*)px;
            float4v hi = *(const float4v*)(px + 4);
            short8 s;
            #pragma unroll
            for (int j = 0; j < 4; j++){
                s[j]     = (short)f2bf(lo[j]);
                s[j + 4] = (short)f2bf(hi[j]);
            }
            ax[rt][ks] = s;
        }
    }

    // ---- Q projection -> per-wave scratch (in Kbuf, pre-K) -> A-frags qf
    u16* qs = Kbuf + w * 4096;            // 8 KB private region; [16][136] used
    short8 qf[2][4];
    #pragma unroll
    for (int rt = 0; rt < 2; rt++){
        #pragma unroll
        for (int ht = 0; ht < 8; ht++){
            short8 bw[4];
            #pragma unroll
            for (int ks = 0; ks < 4; ks++)
                bw[ks] = *(const short8*)(WT + (size_t)(ht*16 + lq)*128 + ks*32 + quad*8);
            float4v c = {0.f,0.f,0.f,0.f};
            #pragma unroll
            for (int ks = 0; ks < 4; ks++)
                c = __builtin_amdgcn_mfma_f32_16x16x32_bf16(ax[rt][ks], bw[ks], c, 0, 0, 0);
            #pragma unroll
            for (int r = 0; r < 4; r++)
                qs[(quad*4 + r)*136 + ht*16 + lq] = f2bf(c[r]);   // D: row=q-row, col=h
        }
        #pragma unroll
        for (int ks = 0; ks < 4; ks++)
            qf[rt][ks] = *(const short8*)(qs + lq*136 + ks*32 + quad*8);  // A: row=lq
    }
    __syncthreads();   // Q scratch dead; Kbuf may now hold K

    // ---- K projection -> Kbuf (permuted) + f32 k output
    #pragma unroll
    for (int rt = 0; rt < 2; rt++){
        #pragma unroll
        for (int ht = 0; ht < 8; ht++){
            short8 bw[4];
            #pragma unroll
            for (int ks = 0; ks < 4; ks++)
                bw[ks] = *(const short8*)(WT + (size_t)16384 + (size_t)(ht*16 + lq)*128 + ks*32 + quad*8);
            float4v c = {0.f,0.f,0.f,0.f};
            #pragma unroll
            for (int ks = 0; ks < 4; ks++)
                c = __builtin_amdgcn_mfma_f32_16x16x32_bf16(ax[rt][ks], bw[ks], c, 0, 0, 0);
            #pragma unroll
            for (int r = 0; r < 4; r++){
                int key = rtg[rt]*16 + quad*4 + r;
                kout[(size_t)key*128 + ht*16 + lq] = c[r];
                Kbuf[(ht>>1)*8192 + key*32 + (ht&1)*16 + lq] = f2bf(c[r]);
            }
        }
    }

    // ---- V projection (f32 out) + V^T (swapped MFMA) -> VTbuf, sharing Wv frags
    #pragma unroll
    for (int ht = 0; ht < 8; ht++){
        short8 bv[4];
        #pragma unroll
        for (int ks = 0; ks < 4; ks++)
            bv[ks] = *(const short8*)(WT + (size_t)2*16384 + (size_t)(ht*16 + lq)*128 + ks*32 + quad*8);
        #pragma unroll
        for (int rt = 0; rt < 2; rt++){
            // V: D[row=t, col=h]
            float4v c = {0.f,0.f,0.f,0.f};
            #pragma unroll
            for (int ks = 0; ks < 4; ks++)
                c = __builtin_amdgcn_mfma_f32_16x16x32_bf16(ax[rt][ks], bv[ks], c, 0, 0, 0);
            #pragma unroll
            for (int r = 0; r < 4; r++)
                vout[(size_t)(rtg[rt]*16 + quad*4 + r)*128 + ht*16 + lq] = c[r];
            // V^T: A = Wv^T rows (h), B = x rows (t) -> D[row=h, col=t]
            float4v ct = {0.f,0.f,0.f,0.f};
            #pragma unroll
            for (int ks = 0; ks < 4; ks++)
                ct = __builtin_amdgcn_mfma_f32_16x16x32_bf16(bv[ks], ax[rt][ks], ct, 0, 0, 0);
            int t = rtg[rt]*16 + lq;
            int e0 = (t>>5)*4096 + (t&31);
            #pragma unroll
            for (int r = 0; r < 4; r++)
                VTbuf[e0 + (ht*16 + quad*4 + r)*32] = f2bf(ct[r]);
        }
    }
    __syncthreads();   // K and V^T images complete

    // ---- S = Q K^T (causal), full row in registers; single-pass softmax
    float4v s[2][16];
    float lsum[2][4];
    #pragma unroll
    for (int rt = 0; rt < 2; rt++){
        int rg = rtg[rt];                 // row-tile index; kt <= rg needed
        #pragma unroll
        for (int kt = 0; kt < 16; kt++){
            if (kt <= rg){
                float4v c = {0.f,0.f,0.f,0.f};
                #pragma unroll
                for (int ks = 0; ks < 4; ks++){
                    short8 bb = *(const short8*)(Kbuf + ks*8192 + (kt*16 + lq)*32 + quad*8);
                    c = __builtin_amdgcn_mfma_f32_16x16x32_bf16(qf[rt][ks], bb, c, 0, 0, 0);
                }
                if (kt == rg){            // diagonal tile: mask key > row
                    #pragma unroll
                    for (int r = 0; r < 4; r++)
                        if (kt*16 + lq > rg*16 + quad*4 + r) c[r] = MASKV;
                }
                s[rt][kt] = c;
            }
        }
        #pragma unroll
        for (int r = 0; r < 4; r++){
            float mx = MASKV;
            #pragma unroll
            for (int kt = 0; kt < 16; kt++)
                if (kt <= rg) mx = fmaxf(mx, s[rt][kt][r]);
            mx = fmaxf(mx, __shfl_xor(mx, 1));
            mx = fmaxf(mx, __shfl_xor(mx, 2));
            mx = fmaxf(mx, __shfl_xor(mx, 4));
            mx = fmaxf(mx, __shfl_xor(mx, 8));
            float rs = 0.f;
            #pragma unroll
            for (int kt = 0; kt < 16; kt++)
                if (kt <= rg){
                    float pv = __expf(s[rt][kt][r] - mx);
                    s[rt][kt][r] = pv;    // S becomes P in place
                    rs += pv;
                }
            rs += __shfl_xor(rs, 1);
            rs += __shfl_xor(rs, 2);
            rs += __shfl_xor(rs, 4);
            rs += __shfl_xor(rs, 8);
            lsum[rt][r] = rs;
        }
    }
    __syncthreads();   // all waves done reading Kbuf (K dead) -> reuse as P scratch

    // ---- O = P V : per 64-key block, P -> per-wave scratch -> A-frags, MFMA with VTbuf
    float4v oacc[2][8];
    #pragma unroll
    for (int rt = 0; rt < 2; rt++)
        #pragma unroll
        for (int o = 0; o < 8; o++) oacc[rt][o] = (float4v){0.f,0.f,0.f,0.f};

    u16* psw = Kbuf + w * 4096;           // private 8 KB; [2][16][72] used (4608 B)
    #pragma unroll
    for (int kb = 0; kb < 4; kb++){
        #pragma unroll
        for (int rt = 0; rt < 2; rt++){
            int rg = rtg[rt];
            if (kb <= (rg >> 2)){
                #pragma unroll
                for (int kt2 = 0; kt2 < 4; kt2++){
                    int kt = kb*4 + kt2;
                    #pragma unroll
                    for (int r = 0; r < 4; r++){
                        float pv = (kt <= rg) ? s[rt][kt][r] : 0.f;
                        psw[rt*1152 + (quad*4 + r)*72 + kt2*16 + lq] = f2bf(pv);
                    }
                }
            }
        }
        #pragma unroll
        for (int rt = 0; rt < 2; rt++){
            if (kb <= (rtg[rt] >> 2)){
                #pragma unroll
                for (int k2 = 0; k2 < 2; k2++){
                    short8 pa = *(const short8*)(psw + rt*1152 + lq*72 + k2*32 + quad*8);
                    #pragma unroll
                    for (int o = 0; o < 8; o++){
                        short8 vb = *(const short8*)(VTbuf + (kb*2 + k2)*4096 + (o*16 + lq)*32 + quad*8);
                        oacc[rt][o] = __builtin_amdgcn_mfma_f32_16x16x32_bf16(pa, vb, oacc[rt][o], 0, 0, 0);
                    }
                }
            }
        }
    }

    // ---- epilogue: out = oacc / lsum
    #pragma unroll
    for (int rt = 0; rt < 2; rt++){
        #pragma unroll
        for (int r = 0; r < 4; r++){
            float inv = 1.0f / lsum[rt][r];
            int row = rtg[rt]*16 + quad*4 + r;
            #pragma unroll
            for (int o = 0; o < 8; o++)
                oout[(size_t)row*128 + o*16 + lq] = oacc[rt][o][r] * inv;
        }
    }
}

extern "C" void kernel_launch(void* const* d_in, const int* in_sizes, int n_in,
                              void* d_out, int out_size, void* d_ws, size_t ws_size,
                              hipStream_t stream){
    const float* x  = (const float*)d_in[0];
    const float* Wk = (const float*)d_in[1];
    const float* Wq = (const float*)d_in[2];
    const float* Wv = (const float*)d_in[3];
    float* out = (float*)d_out;
    u16* WT = (u16*)d_ws;                         // 96 KB (always available)

    wt_kernel   <<<192, 256, 0, stream>>>(Wq, Wk, Wv, WT);
    fused_kernel<<<512, 512, 0, stream>>>(x, WT, out);
}

// Round 5
// 324.309 us; speedup vs baseline: 1.0922x; 1.0922x over previous
//
#include <hip/hip_runtime.h>

typedef unsigned short u16;
typedef __attribute__((ext_vector_type(8))) short short8;
typedef __attribute__((ext_vector_type(4))) float float4v;

#define BTH (512*256*128)   // elements per output tensor
#define MASKV (-30000.0f)

__device__ __forceinline__ u16 f2bf(float f){
    union{float f; unsigned i;} v; v.f = f;
    unsigned x = v.i;
    unsigned r = (x + 0x7FFFu + ((x >> 16) & 1u)) >> 16;  // RNE
    return (u16)r;
}

// ---------------- Kernel 0: f32 weights -> bf16 WT[3][128 n][128 k]; fold C^-0.5 into Wq.
__global__ void wt_kernel(const float* __restrict__ Wq, const float* __restrict__ Wk,
                          const float* __restrict__ Wv, u16* __restrict__ WT){
    int idx = blockIdx.x * 256 + threadIdx.x;   // 0..49151
    int w   = idx >> 14;
    int rem = idx & 16383;
    int n = rem >> 7;
    int k = rem & 127;
    const float* src = (w == 0) ? Wq : (w == 1) ? Wk : Wv;
    float val = src[k * 128 + n];
    if (w == 0) val *= 0.08838834764831845f;    // 128^-0.5
    WT[idx] = f2bf(val);
}

// ============================================================================
// fused_kernel: one block = one batch (512 blocks x 512 threads = 8 waves).
// Projection (q,k,v = x@W) with K and V^T images kept in LDS, then causal
// attention with ONLINE softmax over 4 key-chunks of 64 (S chunk in regs,
// 16 VGPR -- no spill; round-4's full-row S spilled to scratch).
//
// LDS (146 KiB, 1 block/CU):
//   Kbuf  [4 ks][256 key][32]  bf16 (64 KB)   K permuted: Kbuf[h>>5][key][h&31]
//   VTbuf [8 ck][128 h][32]    bf16 (64 KB)   V^T: VTbuf[t>>5][h][t&31]
//         -- during Q phase, VTbuf doubles as per-wave 8 KB Q-transpose scratch
//            (round-4 used 4 KB slices of Kbuf and OVERFLOWED: 4352B > 4096B).
//   ps    [8 wave][1152]       bf16 (18 KB)   per-wave P transpose scratch
//         (dedicated: Kbuf stays live across all chunks in the online scheme).
//
// Wave w owns row-tiles {w, w+8} (interleaved -> causal load balance).
// 2 __syncthreads() total; all other LDS reuse is same-wave (lgkmcnt-ordered).
// ============================================================================
__global__ __launch_bounds__(512, 1) void fused_kernel(const float* __restrict__ x,
                                                       const u16* __restrict__ WT,
                                                       float* __restrict__ dout){
    __shared__ u16 Kbuf [4 * 256 * 32];   // 64 KB
    __shared__ u16 VTbuf[8 * 128 * 32];   // 64 KB
    __shared__ u16 ps   [8 * 1152];       // 18 KB

    int b = blockIdx.x;
    int tid = threadIdx.x;
    int w = tid >> 6, lane = tid & 63, lq = lane & 15, quad = lane >> 4;

    const float* xb   = x    + (size_t)b * 256 * 128;
    float*       oout = dout + (size_t)b * 256 * 128;
    float*       kout = dout + (size_t)BTH     + (size_t)b * 256 * 128;
    float*       vout = dout + (size_t)2 * BTH + (size_t)b * 256 * 128;

    const int rtg[2] = { w, w + 8 };      // this wave's global row-tile indices

    // ---- x fragments for own 32 rows (f32 -> bf16), registers only
    short8 ax[2][4];
    #pragma unroll
    for (int rt = 0; rt < 2; rt++){
        #pragma unroll
        for (int ks = 0; ks < 4; ks++){
            const float* px = xb + (size_t)(rtg[rt]*16 + lq)*128 + ks*32 + quad*8;
            float4v lo = *(const float4v*)px;
            float4v hi = *(const float4v*)(px + 4);
            short8 s;
            #pragma unroll
            for (int j = 0; j < 4; j++){
                s[j]     = (short)f2bf(lo[j]);
                s[j + 4] = (short)f2bf(hi[j]);
            }
            ax[rt][ks] = s;
        }
    }

    // ---- Q projection -> per-wave scratch (VTbuf slice, 8KB >= 4352B) -> A-frags
    u16* qs = VTbuf + w * 4096;           // u16 units: 8192 B per wave
    short8 qf[2][4];
    #pragma unroll
    for (int rt = 0; rt < 2; rt++){
        #pragma unroll
        for (int ht = 0; ht < 8; ht++){
            short8 bw[4];
            #pragma unroll
            for (int ks = 0; ks < 4; ks++)
                bw[ks] = *(const short8*)(WT + (size_t)(ht*16 + lq)*128 + ks*32 + quad*8);
            float4v c = {0.f,0.f,0.f,0.f};
            #pragma unroll
            for (int ks = 0; ks < 4; ks++)
                c = __builtin_amdgcn_mfma_f32_16x16x32_bf16(ax[rt][ks], bw[ks], c, 0, 0, 0);
            #pragma unroll
            for (int r = 0; r < 4; r++)
                qs[(quad*4 + r)*136 + ht*16 + lq] = f2bf(c[r]);   // D: row=q-row, col=h
        }
        #pragma unroll
        for (int ks = 0; ks < 4; ks++)
            qf[rt][ks] = *(const short8*)(qs + lq*136 + ks*32 + quad*8);  // A: row=lq
    }
    __syncthreads();   // Q scratch dead; VTbuf/Kbuf may now hold V^T/K

    // ---- K projection -> Kbuf (permuted) + f32 k output
    #pragma unroll
    for (int rt = 0; rt < 2; rt++){
        #pragma unroll
        for (int ht = 0; ht < 8; ht++){
            short8 bw[4];
            #pragma unroll
            for (int ks = 0; ks < 4; ks++)
                bw[ks] = *(const short8*)(WT + (size_t)16384 + (size_t)(ht*16 + lq)*128 + ks*32 + quad*8);
            float4v c = {0.f,0.f,0.f,0.f};
            #pragma unroll
            for (int ks = 0; ks < 4; ks++)
                c = __builtin_amdgcn_mfma_f32_16x16x32_bf16(ax[rt][ks], bw[ks], c, 0, 0, 0);
            #pragma unroll
            for (int r = 0; r < 4; r++){
                int key = rtg[rt]*16 + quad*4 + r;
                kout[(size_t)key*128 + ht*16 + lq] = c[r];
                Kbuf[(ht>>1)*8192 + key*32 + (ht&1)*16 + lq] = f2bf(c[r]);
            }
        }
    }

    // ---- V projection (f32 out) + V^T (swapped MFMA) -> VTbuf, sharing Wv frags
    #pragma unroll
    for (int ht = 0; ht < 8; ht++){
        short8 bv[4];
        #pragma unroll
        for (int ks = 0; ks < 4; ks++)
            bv[ks] = *(const short8*)(WT + (size_t)2*16384 + (size_t)(ht*16 + lq)*128 + ks*32 + quad*8);
        #pragma unroll
        for (int rt = 0; rt < 2; rt++){
            // V: D[row=t, col=h]
            float4v c = {0.f,0.f,0.f,0.f};
            #pragma unroll
            for (int ks = 0; ks < 4; ks++)
                c = __builtin_amdgcn_mfma_f32_16x16x32_bf16(ax[rt][ks], bv[ks], c, 0, 0, 0);
            #pragma unroll
            for (int r = 0; r < 4; r++)
                vout[(size_t)(rtg[rt]*16 + quad*4 + r)*128 + ht*16 + lq] = c[r];
            // V^T: A = Wv^T rows (h), B = x rows (t) -> D[row=h, col=t]
            float4v ct = {0.f,0.f,0.f,0.f};
            #pragma unroll
            for (int ks = 0; ks < 4; ks++)
                ct = __builtin_amdgcn_mfma_f32_16x16x32_bf16(bv[ks], ax[rt][ks], ct, 0, 0, 0);
            int t = rtg[rt]*16 + lq;
            int e0 = (t>>5)*4096 + (t&31);
            #pragma unroll
            for (int r = 0; r < 4; r++)
                VTbuf[e0 + (ht*16 + quad*4 + r)*32] = f2bf(ct[r]);
        }
    }
    __syncthreads();   // K and V^T images complete

    // ---- online-softmax attention over 4 key-chunks of 64
    float4v oacc[2][8];
    float mrun[2][4], lrun[2][4];
    #pragma unroll
    for (int rt = 0; rt < 2; rt++){
        #pragma unroll
        for (int o = 0; o < 8; o++) oacc[rt][o] = (float4v){0.f,0.f,0.f,0.f};
        #pragma unroll
        for (int r = 0; r < 4; r++){ mrun[rt][r] = MASKV; lrun[rt][r] = 0.f; }
    }
    u16* psw = ps + w * 1152;             // [16 rows][72 keys] bf16, single rt at a time

    #pragma unroll
    for (int kb = 0; kb < 4; kb++){
        #pragma unroll
        for (int rt = 0; rt < 2; rt++){
            int rg = rtg[rt];
            if (kb*4 > rg) continue;      // chunk fully above diagonal (wave-uniform)

            // S chunk = Q K^T : 16 rows x 64 keys
            float4v s4[4];
            #pragma unroll
            for (int kt2 = 0; kt2 < 4; kt2++){
                int kt = kb*4 + kt2;
                float4v c = {MASKV, MASKV, MASKV, MASKV};
                if (kt <= rg){
                    c = (float4v){0.f,0.f,0.f,0.f};
                    #pragma unroll
                    for (int ks = 0; ks < 4; ks++){
                        short8 bb = *(const short8*)(Kbuf + ks*8192 + (kt*16 + lq)*32 + quad*8);
                        c = __builtin_amdgcn_mfma_f32_16x16x32_bf16(qf[rt][ks], bb, c, 0, 0, 0);
                    }
                    #pragma unroll
                    for (int r = 0; r < 4; r++)
                        c[r] = fminf(fmaxf(c[r], MASKV), 30000.0f);   // NaN/inf scrub
                    if (kt == rg){        // diagonal tile: mask key > row
                        #pragma unroll
                        for (int r = 0; r < 4; r++)
                            if (kt*16 + lq > rg*16 + quad*4 + r) c[r] = MASKV;
                    }
                }
                s4[kt2] = c;
            }
            // online softmax update (quad group's 16 lanes hold one row's 64 cols)
            #pragma unroll
            for (int r = 0; r < 4; r++){
                float mx = fmaxf(fmaxf(s4[0][r], s4[1][r]), fmaxf(s4[2][r], s4[3][r]));
                mx = fmaxf(mx, __shfl_xor(mx, 1));
                mx = fmaxf(mx, __shfl_xor(mx, 2));
                mx = fmaxf(mx, __shfl_xor(mx, 4));
                mx = fmaxf(mx, __shfl_xor(mx, 8));
                float mnew = fmaxf(mrun[rt][r], mx);
                float alpha = __expf(mrun[rt][r] - mnew);
                float rs = 0.f;
                #pragma unroll
                for (int kt2 = 0; kt2 < 4; kt2++){
                    float pv = __expf(s4[kt2][r] - mnew);
                    s4[kt2][r] = pv;      // S becomes P in place
                    rs += pv;
                }
                rs += __shfl_xor(rs, 1);
                rs += __shfl_xor(rs, 2);
                rs += __shfl_xor(rs, 4);
                rs += __shfl_xor(rs, 8);
                lrun[rt][r] = lrun[rt][r] * alpha + rs;
                mrun[rt][r] = mnew;
                #pragma unroll
                for (int o = 0; o < 8; o++) oacc[rt][o][r] *= alpha;
            }
            // P: C/D-layout -> per-wave LDS -> A-layout (same-wave ordering)
            #pragma unroll
            for (int kt2 = 0; kt2 < 4; kt2++)
                #pragma unroll
                for (int r = 0; r < 4; r++)
                    psw[(quad*4 + r)*72 + kt2*16 + lq] = f2bf(s4[kt2][r]);
            short8 pa0 = *(const short8*)(psw + lq*72 + quad*8);
            short8 pa1 = *(const short8*)(psw + lq*72 + 32 + quad*8);
            // O += P V  (V^T chunk kb resident in VTbuf)
            #pragma unroll
            for (int k2 = 0; k2 < 2; k2++){
                short8 pa = (k2 == 0) ? pa0 : pa1;
                #pragma unroll
                for (int o = 0; o < 8; o++){
                    short8 vb = *(const short8*)(VTbuf + (kb*2 + k2)*4096 + (o*16 + lq)*32 + quad*8);
                    oacc[rt][o] = __builtin_amdgcn_mfma_f32_16x16x32_bf16(pa, vb, oacc[rt][o], 0, 0, 0);
                }
            }
        }
    }

    // ---- epilogue: out = oacc / lrun
    #pragma unroll
    for (int rt = 0; rt < 2; rt++){
        #pragma unroll
        for (int r = 0; r < 4; r++){
            float inv = 1.0f / lrun[rt][r];
            int row = rtg[rt]*16 + quad*4 + r;
            #pragma unroll
            for (int o = 0; o < 8; o++)
                oout[(size_t)row*128 + o*16 + lq] = oacc[rt][o][r] * inv;
        }
    }
}

extern "C" void kernel_launch(void* const* d_in, const int* in_sizes, int n_in,
                              void* d_out, int out_size, void* d_ws, size_t ws_size,
                              hipStream_t stream){
    const float* x  = (const float*)d_in[0];
    const float* Wk = (const float*)d_in[1];
    const float* Wq = (const float*)d_in[2];
    const float* Wv = (const float*)d_in[3];
    float* out = (float*)d_out;
    u16* WT = (u16*)d_ws;                         // 96 KB (always available)

    wt_kernel   <<<192, 256, 0, stream>>>(Wq, Wk, Wv, WT);
    fused_kernel<<<512, 512, 0, stream>>>(x, WT, out);
}

// Round 6
// 323.001 us; speedup vs baseline: 1.0966x; 1.0041x over previous
//
#include <hip/hip_runtime.h>

typedef unsigned short u16;
typedef __attribute__((ext_vector_type(8))) short short8;
typedef __attribute__((ext_vector_type(4))) float float4v;

#define BTH (512*256*128)   // elements per output tensor
#define MASKV (-30000.0f)

__device__ __forceinline__ u16 f2bf(float f){
    union{float f; unsigned i;} v; v.f = f;
    unsigned x = v.i;
    unsigned r = (x + 0x7FFFu + ((x >> 16) & 1u)) >> 16;  // RNE
    return (u16)r;
}

// ---------------- Kernel 0: f32 weights -> bf16 WT[3][128 n][128 k]; fold C^-0.5 into Wq.
__global__ void wt_kernel(const float* __restrict__ Wq, const float* __restrict__ Wk,
                          const float* __restrict__ Wv, u16* __restrict__ WT){
    int idx = blockIdx.x * 256 + threadIdx.x;   // 0..49151
    int w   = idx >> 14;
    int rem = idx & 16383;
    int n = rem >> 7;
    int k = rem & 127;
    const float* src = (w == 0) ? Wq : (w == 1) ? Wk : Wv;
    float val = src[k * 128 + n];
    if (w == 0) val *= 0.08838834764831845f;    // 128^-0.5
    WT[idx] = f2bf(val);
}

// ============================================================================
// fused_kernel: one block = one batch, 1024 threads = 16 waves (4 waves/SIMD,
// 2x round-5's occupancy -- that round was latency-bound at 2 waves/SIMD).
// Each wave owns ONE 16-row tile; TILE[] permutation balances the causal
// triangle across both contiguous-4 and stride-4 wave->SIMD groupings.
//
// LDS (160 KiB exactly, 1 block/CU):
//   Kbuf  [4 ks][256 key][32]  bf16 (64 KB)  K permuted: Kbuf[h>>5][key][h&31]
//         -- pre-K, each wave's 4 KB slice = Q-transpose scratch [16][128]
//   VTbuf [8 ck][128 h][32]    bf16 (64 KB)  V^T: VTbuf[t>>5][h][t&31]
//   ps    [16 wave][16][64]    bf16 (32 KB)  per-wave P transpose (unpadded:
//         16-way conflict on 2 reads/pass -- cheap vs doubled occupancy)
// 2 __syncthreads() total; per-wave LDS reuse is same-wave (lgkmcnt-ordered).
// ============================================================================
__global__ __launch_bounds__(1024, 4) void fused_kernel(const float* __restrict__ x,
                                                        const u16* __restrict__ WT,
                                                        float* __restrict__ dout){
    __shared__ u16 Kbuf [4 * 256 * 32];   // 64 KB
    __shared__ u16 VTbuf[8 * 128 * 32];   // 64 KB
    __shared__ u16 ps   [16 * 1024];      // 32 KB

    int b = blockIdx.x;
    int tid = threadIdx.x;
    int w = tid >> 6, lane = tid & 63, lq = lane & 15, quad = lane >> 4;

    // balanced causal tile assignment (weights t+1; quads sum 34, stride-4 sums 32-36)
    const int TILE[16] = {0,15,7,8, 14,1,9,6, 2,13,5,10, 12,3,11,4};
    int rg = TILE[w];

    const float* xb   = x    + (size_t)b * 256 * 128;
    float*       oout = dout + (size_t)b * 256 * 128;
    float*       kout = dout + (size_t)BTH     + (size_t)b * 256 * 128;
    float*       vout = dout + (size_t)2 * BTH + (size_t)b * 256 * 128;

    // ---- x fragments for own 16 rows (f32 -> bf16), registers only
    short8 ax[4];
    #pragma unroll
    for (int ks = 0; ks < 4; ks++){
        const float* px = xb + (size_t)(rg*16 + lq)*128 + ks*32 + quad*8;
        float4v lo = *(const float4v*)px;
        float4v hi = *(const float4v*)(px + 4);
        short8 s;
        #pragma unroll
        for (int j = 0; j < 4; j++){
            s[j]     = (short)f2bf(lo[j]);
            s[j + 4] = (short)f2bf(hi[j]);
        }
        ax[ks] = s;
    }

    // ---- Q projection -> per-wave scratch (Kbuf slice, [16][128] = 4096 B) -> A-frags
    u16* qs = Kbuf + w * 2048;            // u16 units
    short8 qf[4];
    {
        #pragma unroll
        for (int ht = 0; ht < 8; ht++){
            short8 bw[4];
            #pragma unroll
            for (int ks = 0; ks < 4; ks++)
                bw[ks] = *(const short8*)(WT + (size_t)(ht*16 + lq)*128 + ks*32 + quad*8);
            float4v c = {0.f,0.f,0.f,0.f};
            #pragma unroll
            for (int ks = 0; ks < 4; ks++)
                c = __builtin_amdgcn_mfma_f32_16x16x32_bf16(ax[ks], bw[ks], c, 0, 0, 0);
            #pragma unroll
            for (int r = 0; r < 4; r++)
                qs[(quad*4 + r)*128 + ht*16 + lq] = f2bf(c[r]);   // D: row=q-row, col=h
        }
        #pragma unroll
        for (int ks = 0; ks < 4; ks++)
            qf[ks] = *(const short8*)(qs + lq*128 + ks*32 + quad*8);  // A: row=lq
    }
    __syncthreads();   // Q scratch dead; Kbuf may now hold K

    // ---- K projection -> Kbuf (permuted) + f32 k output
    #pragma unroll
    for (int ht = 0; ht < 8; ht++){
        short8 bw[4];
        #pragma unroll
        for (int ks = 0; ks < 4; ks++)
            bw[ks] = *(const short8*)(WT + (size_t)16384 + (size_t)(ht*16 + lq)*128 + ks*32 + quad*8);
        float4v c = {0.f,0.f,0.f,0.f};
        #pragma unroll
        for (int ks = 0; ks < 4; ks++)
            c = __builtin_amdgcn_mfma_f32_16x16x32_bf16(ax[ks], bw[ks], c, 0, 0, 0);
        #pragma unroll
        for (int r = 0; r < 4; r++){
            int key = rg*16 + quad*4 + r;
            kout[(size_t)key*128 + ht*16 + lq] = c[r];
            Kbuf[(ht>>1)*8192 + key*32 + (ht&1)*16 + lq] = f2bf(c[r]);
        }
    }

    // ---- V projection (f32 out) + V^T (swapped MFMA) -> VTbuf, sharing Wv frags
    #pragma unroll
    for (int ht = 0; ht < 8; ht++){
        short8 bv[4];
        #pragma unroll
        for (int ks = 0; ks < 4; ks++)
            bv[ks] = *(const short8*)(WT + (size_t)2*16384 + (size_t)(ht*16 + lq)*128 + ks*32 + quad*8);
        // V: D[row=t, col=h]
        float4v c = {0.f,0.f,0.f,0.f};
        #pragma unroll
        for (int ks = 0; ks < 4; ks++)
            c = __builtin_amdgcn_mfma_f32_16x16x32_bf16(ax[ks], bv[ks], c, 0, 0, 0);
        #pragma unroll
        for (int r = 0; r < 4; r++)
            vout[(size_t)(rg*16 + quad*4 + r)*128 + ht*16 + lq] = c[r];
        // V^T: A = Wv^T rows (h), B = x rows (t) -> D[row=h, col=t]
        float4v ct = {0.f,0.f,0.f,0.f};
        #pragma unroll
        for (int ks = 0; ks < 4; ks++)
            ct = __builtin_amdgcn_mfma_f32_16x16x32_bf16(bv[ks], ax[ks], ct, 0, 0, 0);
        int t = rg*16 + lq;
        int e0 = (t>>5)*4096 + (t&31);
        #pragma unroll
        for (int r = 0; r < 4; r++)
            VTbuf[e0 + (ht*16 + quad*4 + r)*32] = f2bf(ct[r]);
    }
    __syncthreads();   // K and V^T images complete

    // ---- online-softmax attention over key-chunks of 64
    float4v oacc[8];
    float mrun[4], lrun[4];
    #pragma unroll
    for (int o = 0; o < 8; o++) oacc[o] = (float4v){0.f,0.f,0.f,0.f};
    #pragma unroll
    for (int r = 0; r < 4; r++){ mrun[r] = MASKV; lrun[r] = 0.f; }
    u16* psw = ps + w * 1024;             // [16 rows][64 keys] bf16

    #pragma unroll
    for (int kb = 0; kb < 4; kb++){
        if (kb*4 > rg) continue;          // chunk fully above diagonal (wave-uniform)

        // S chunk = Q K^T : 16 rows x 64 keys
        float4v s4[4];
        #pragma unroll
        for (int kt2 = 0; kt2 < 4; kt2++){
            int kt = kb*4 + kt2;
            float4v c = {MASKV, MASKV, MASKV, MASKV};
            if (kt <= rg){
                c = (float4v){0.f,0.f,0.f,0.f};
                #pragma unroll
                for (int ks = 0; ks < 4; ks++){
                    short8 bb = *(const short8*)(Kbuf + ks*8192 + (kt*16 + lq)*32 + quad*8);
                    c = __builtin_amdgcn_mfma_f32_16x16x32_bf16(qf[ks], bb, c, 0, 0, 0);
                }
                #pragma unroll
                for (int r = 0; r < 4; r++)
                    c[r] = fminf(fmaxf(c[r], MASKV), 30000.0f);   // NaN/inf scrub
                if (kt == rg){            // diagonal tile: mask key > row
                    #pragma unroll
                    for (int r = 0; r < 4; r++)
                        if (kt*16 + lq > rg*16 + quad*4 + r) c[r] = MASKV;
                }
            }
            s4[kt2] = c;
        }
        // online softmax update (quad group's 16 lanes hold one row's 64 cols)
        #pragma unroll
        for (int r = 0; r < 4; r++){
            float mx = fmaxf(fmaxf(s4[0][r], s4[1][r]), fmaxf(s4[2][r], s4[3][r]));
            mx = fmaxf(mx, __shfl_xor(mx, 1));
            mx = fmaxf(mx, __shfl_xor(mx, 2));
            mx = fmaxf(mx, __shfl_xor(mx, 4));
            mx = fmaxf(mx, __shfl_xor(mx, 8));
            float mnew = fmaxf(mrun[r], mx);
            float alpha = __expf(mrun[r] - mnew);
            float rs = 0.f;
            #pragma unroll
            for (int kt2 = 0; kt2 < 4; kt2++){
                float pv = __expf(s4[kt2][r] - mnew);
                s4[kt2][r] = pv;          // S becomes P in place
                rs += pv;
            }
            rs += __shfl_xor(rs, 1);
            rs += __shfl_xor(rs, 2);
            rs += __shfl_xor(rs, 4);
            rs += __shfl_xor(rs, 8);
            lrun[r] = lrun[r] * alpha + rs;
            mrun[r] = mnew;
            #pragma unroll
            for (int o = 0; o < 8; o++) oacc[o][r] *= alpha;
        }
        // P: C/D-layout -> per-wave LDS -> A-layout (same-wave ordering)
        #pragma unroll
        for (int kt2 = 0; kt2 < 4; kt2++)
            #pragma unroll
            for (int r = 0; r < 4; r++)
                psw[(quad*4 + r)*64 + kt2*16 + lq] = f2bf(s4[kt2][r]);
        short8 pa0 = *(const short8*)(psw + lq*64 + quad*8);
        short8 pa1 = *(const short8*)(psw + lq*64 + 32 + quad*8);
        // O += P V  (V^T chunk kb resident in VTbuf)
        #pragma unroll
        for (int k2 = 0; k2 < 2; k2++){
            short8 pa = (k2 == 0) ? pa0 : pa1;
            #pragma unroll
            for (int o = 0; o < 8; o++){
                short8 vb = *(const short8*)(VTbuf + (kb*2 + k2)*4096 + (o*16 + lq)*32 + quad*8);
                oacc[o] = __builtin_amdgcn_mfma_f32_16x16x32_bf16(pa, vb, oacc[o], 0, 0, 0);
            }
        }
    }

    // ---- epilogue: out = oacc / lrun
    #pragma unroll
    for (int r = 0; r < 4; r++){
        float inv = 1.0f / lrun[r];
        int row = rg*16 + quad*4 + r;
        #pragma unroll
        for (int o = 0; o < 8; o++)
            oout[(size_t)row*128 + o*16 + lq] = oacc[o][r] * inv;
    }
}

extern "C" void kernel_launch(void* const* d_in, const int* in_sizes, int n_in,
                              void* d_out, int out_size, void* d_ws, size_t ws_size,
                              hipStream_t stream){
    const float* x  = (const float*)d_in[0];
    const float* Wk = (const float*)d_in[1];
    const float* Wq = (const float*)d_in[2];
    const float* Wv = (const float*)d_in[3];
    float* out = (float*)d_out;
    u16* WT = (u16*)d_ws;                         // 96 KB (always available)

    wt_kernel   <<<192,  256, 0, stream>>>(Wq, Wk, Wv, WT);
    fused_kernel<<<512, 1024, 0, stream>>>(x, WT, out);
}